// Round 1
// baseline (927.527 us; speedup 1.0000x reference)
//
#include <hip/hip_runtime.h>
#include <math.h>

#define H 4
#define HD 16
#define DIM 64
#define NEG_SLOPE 0.2f
#define EPS_SM 1e-8f
#define EPS_LN 1e-5f

// ---------------------------------------------------------------------------
// Kernel 1: h = x @ W_node  (64x64), acc = h (residual pre-seed),
//           a_src[n][h] = <h[n,h,:], attn_src[h,:]>, a_dst likewise.
// 16 rows per 256-thread block; W_node staged in LDS (16 KB).
// ---------------------------------------------------------------------------
__global__ __launch_bounds__(256) void k_node(
    const float* __restrict__ x, const float* __restrict__ Wn,
    const float* __restrict__ attn_src, const float* __restrict__ attn_dst,
    float* __restrict__ h, float* __restrict__ acc,
    float* __restrict__ a_src, float* __restrict__ a_dst, int n)
{
    __shared__ float Ws[64][64];
    __shared__ float xs[16][64];
    __shared__ float hs[16][64];
    const int tid = threadIdx.x;
    const int row0 = blockIdx.x * 16;

    for (int i = tid; i < 64 * 64; i += 256) Ws[i >> 6][i & 63] = Wn[i];
    for (int i = tid; i < 16 * 64; i += 256) {
        int r = row0 + (i >> 6);
        xs[i >> 6][i & 63] = (r < n) ? x[(size_t)r * 64 + (i & 63)] : 0.f;
    }
    __syncthreads();

    const int col = tid & 63;
    const int r0  = tid >> 6;   // 0..3
    float a0 = 0.f, a1 = 0.f, a2 = 0.f, a3 = 0.f;
    #pragma unroll
    for (int k = 0; k < 64; ++k) {
        float w = Ws[k][col];
        a0 += xs[r0     ][k] * w;
        a1 += xs[r0 +  4][k] * w;
        a2 += xs[r0 +  8][k] * w;
        a3 += xs[r0 + 12][k] * w;
    }
    float av[4] = {a0, a1, a2, a3};
    #pragma unroll
    for (int j = 0; j < 4; ++j) {
        int rl = r0 + 4 * j;
        int r  = row0 + rl;
        hs[rl][col] = av[j];
        if (r < n) {
            h  [(size_t)r * 64 + col] = av[j];
            acc[(size_t)r * 64 + col] = av[j];
        }
    }
    __syncthreads();

    if (tid < 64) {
        int rl = tid >> 2;   // 0..15
        int hh = tid & 3;    // 0..3
        float s1 = 0.f, s2 = 0.f;
        #pragma unroll
        for (int d = 0; d < HD; ++d) {
            float v = hs[rl][hh * HD + d];
            s1 += v * attn_src[hh * HD + d];
            s2 += v * attn_dst[hh * HD + d];
        }
        int r = row0 + rl;
        if (r < n) {
            a_src[(size_t)r * 4 + hh] = s1;
            a_dst[(size_t)r * 4 + hh] = s2;
        }
    }
}

// ---------------------------------------------------------------------------
// Kernel 2: per edge — e_score = edge_attr @ W_edge, raw attn =
// lrelu(a_src[src]+a_dst[dst]+e_score); store attn_e; atomicMax into
// attn_max[dst] (values >= 0 so int-bit compare == float compare).
// ---------------------------------------------------------------------------
__global__ __launch_bounds__(256) void k_edge_score(
    const int* __restrict__ src, const int* __restrict__ dst,
    const float* __restrict__ ea, const float* __restrict__ We,
    const float* __restrict__ a_src, const float* __restrict__ a_dst,
    float* __restrict__ attn_e, float* __restrict__ attn_max, int E)
{
    __shared__ float Wes[64];   // W_edge [16][4]
    const int tid = threadIdx.x;
    if (tid < 64) Wes[tid] = We[tid];
    __syncthreads();

    int e = blockIdx.x * 256 + tid;
    if (e >= E) return;

    int s = src[e];
    int d = dst[e];

    const float4* ea4 = (const float4*)(ea + (size_t)e * 16);
    float4 v0 = ea4[0], v1 = ea4[1], v2 = ea4[2], v3 = ea4[3];
    float eav[16] = {v0.x, v0.y, v0.z, v0.w, v1.x, v1.y, v1.z, v1.w,
                     v2.x, v2.y, v2.z, v2.w, v3.x, v3.y, v3.z, v3.w};
    float esc[H] = {0.f, 0.f, 0.f, 0.f};
    #pragma unroll
    for (int k = 0; k < 16; ++k) {
        #pragma unroll
        for (int hh = 0; hh < H; ++hh) esc[hh] += eav[k] * Wes[k * 4 + hh];
    }

    float4 as = *(const float4*)(a_src + (size_t)s * 4);
    float4 ad = *(const float4*)(a_dst + (size_t)d * 4);
    float a[4] = {as.x + ad.x + esc[0], as.y + ad.y + esc[1],
                  as.z + ad.z + esc[2], as.w + ad.w + esc[3]};
    #pragma unroll
    for (int hh = 0; hh < H; ++hh) a[hh] = (a[hh] >= 0.f) ? a[hh] : NEG_SLOPE * a[hh];

    *(float4*)(attn_e + (size_t)e * 4) = make_float4(a[0], a[1], a[2], a[3]);

    #pragma unroll
    for (int hh = 0; hh < H; ++hh) {
        float m = fmaxf(a[hh], 0.f);
        if (m > 0.f)
            atomicMax((int*)(attn_max + (size_t)d * 4 + hh), __float_as_int(m));
    }
}

// ---------------------------------------------------------------------------
// Kernel 3: attn_sum[dst] += exp(attn - max[dst])
// ---------------------------------------------------------------------------
__global__ __launch_bounds__(256) void k_edge_sum(
    const int* __restrict__ dst, const float* __restrict__ attn_e,
    const float* __restrict__ attn_max, float* __restrict__ attn_sum, int E)
{
    int e = blockIdx.x * 256 + threadIdx.x;
    if (e >= E) return;
    int d = dst[e];
    float4 a = ((const float4*)attn_e)[e];
    float4 m = ((const float4*)attn_max)[d];
    atomicAdd(attn_sum + (size_t)d * 4 + 0, __expf(a.x - m.x));
    atomicAdd(attn_sum + (size_t)d * 4 + 1, __expf(a.y - m.y));
    atomicAdd(attn_sum + (size_t)d * 4 + 2, __expf(a.z - m.z));
    atomicAdd(attn_sum + (size_t)d * 4 + 3, __expf(a.w - m.w));
}

// ---------------------------------------------------------------------------
// Kernel 4: wave-per-edge scatter. lane = output column (head = lane/16).
// coeff = exp(a - m) / (sum + eps); acc[dst] += h[src] * coeff.
// ---------------------------------------------------------------------------
__global__ __launch_bounds__(256) void k_scatter(
    const int* __restrict__ src, const int* __restrict__ dst,
    const float* __restrict__ attn_e, const float* __restrict__ attn_max,
    const float* __restrict__ attn_sum, const float* __restrict__ h,
    float* __restrict__ acc, int E)
{
    int gid  = blockIdx.x * 256 + threadIdx.x;
    int e    = gid >> 6;
    int lane = gid & 63;
    if (e >= E) return;
    int s  = src[e];
    int d  = dst[e];
    int hh = lane >> 4;
    float a  = attn_e  [(size_t)e * 4 + hh];
    float m  = attn_max[(size_t)d * 4 + hh];
    float sm = attn_sum[(size_t)d * 4 + hh];
    float coeff = __expf(a - m) / (sm + EPS_SM);
    float msg = h[(size_t)s * 64 + lane] * coeff;
    atomicAdd(acc + (size_t)d * 64 + lane, msg);
}

// ---------------------------------------------------------------------------
// Kernel 5: LayerNorm. wave per row (64 lanes = 64 cols), y = acc (residual
// already seeded with h).
// ---------------------------------------------------------------------------
__global__ __launch_bounds__(256) void k_ln(
    const float* __restrict__ acc, const float* __restrict__ gamma,
    const float* __restrict__ beta, float* __restrict__ out, int n)
{
    int gid  = blockIdx.x * 256 + threadIdx.x;
    int r    = gid >> 6;
    int lane = gid & 63;
    if (r >= n) return;
    float y = acc[(size_t)r * 64 + lane];
    float sum = y;
    #pragma unroll
    for (int off = 32; off; off >>= 1) sum += __shfl_xor(sum, off, 64);
    float mu = sum * (1.f / 64.f);
    float dv = y - mu;
    float vs = dv * dv;
    #pragma unroll
    for (int off = 32; off; off >>= 1) vs += __shfl_xor(vs, off, 64);
    float var = vs * (1.f / 64.f);
    out[(size_t)r * 64 + lane] = dv * rsqrtf(var + EPS_LN) * gamma[lane] + beta[lane];
}

// ---------------------------------------------------------------------------
extern "C" void kernel_launch(void* const* d_in, const int* in_sizes, int n_in,
                              void* d_out, int out_size, void* d_ws, size_t ws_size,
                              hipStream_t stream)
{
    const float* x     = (const float*)d_in[0];
    const int*   ei    = (const int*)  d_in[1];
    const float* ea    = (const float*)d_in[2];
    const float* Wn    = (const float*)d_in[3];
    const float* We    = (const float*)d_in[4];
    const float* asrcW = (const float*)d_in[5];
    const float* adstW = (const float*)d_in[6];
    const float* gamma = (const float*)d_in[7];
    const float* beta  = (const float*)d_in[8];
    float* out = (float*)d_out;

    const int n = in_sizes[0] / DIM;
    const int E = in_sizes[1] / 2;
    const int* src = ei;
    const int* dst = ei + E;

    float* ws = (float*)d_ws;
    size_t off = 0;
    float* h_       = ws + off; off += (size_t)n * 64;
    float* acc      = ws + off; off += (size_t)n * 64;
    float* a_src    = ws + off; off += (size_t)n * 4;
    float* a_dst    = ws + off; off += (size_t)n * 4;
    float* attn_max = ws + off; off += (size_t)n * 4;
    float* attn_sum = ws + off; off += (size_t)n * 4;
    float* attn_e   = ws + off; off += (size_t)E * 4;

    // zero attn_max and attn_sum (contiguous)
    hipMemsetAsync(attn_max, 0, (size_t)n * 8 * sizeof(float), stream);

    k_node<<<(n + 15) / 16, 256, 0, stream>>>(x, Wn, asrcW, adstW, h_, acc, a_src, a_dst, n);
    k_edge_score<<<(E + 255) / 256, 256, 0, stream>>>(src, dst, ea, We, a_src, a_dst, attn_e, attn_max, E);
    k_edge_sum<<<(E + 255) / 256, 256, 0, stream>>>(dst, attn_e, attn_max, attn_sum, E);
    {
        long long total = (long long)E * 64;
        int blocks = (int)((total + 255) / 256);
        k_scatter<<<blocks, 256, 0, stream>>>(src, dst, attn_e, attn_max, attn_sum, h_, acc, E);
    }
    k_ln<<<((n * 64) + 255) / 256, 256, 0, stream>>>(acc, gamma, beta, out, n);
}

// Round 2
// 471.076 us; speedup vs baseline: 1.9690x; 1.9690x over previous
//
#include <hip/hip_runtime.h>
#include <math.h>

#define H 4
#define HD 16
#define NEG_SLOPE 0.2f
#define EPS_SM 1e-8f
#define EPS_LN 1e-5f

// ---------------------------------------------------------------------------
// Kernel 1: h = x @ W_node (64x64), a_src[n][h] = <h[n,h,:], attn_src[h,:]>,
// a_dst likewise. 16 rows per 256-thread block; W_node staged in LDS.
// ---------------------------------------------------------------------------
__global__ __launch_bounds__(256) void k_node(
    const float* __restrict__ x, const float* __restrict__ Wn,
    const float* __restrict__ attn_src, const float* __restrict__ attn_dst,
    float* __restrict__ h, float* __restrict__ a_src, float* __restrict__ a_dst,
    int n)
{
    __shared__ float Ws[64][64];
    __shared__ float xs[16][64];
    __shared__ float hs[16][64];
    const int tid = threadIdx.x;
    const int row0 = blockIdx.x * 16;

    for (int i = tid; i < 64 * 64; i += 256) Ws[i >> 6][i & 63] = Wn[i];
    for (int i = tid; i < 16 * 64; i += 256) {
        int r = row0 + (i >> 6);
        xs[i >> 6][i & 63] = (r < n) ? x[(size_t)r * 64 + (i & 63)] : 0.f;
    }
    __syncthreads();

    const int col = tid & 63;
    const int r0  = tid >> 6;   // 0..3
    float a0 = 0.f, a1 = 0.f, a2 = 0.f, a3 = 0.f;
    #pragma unroll
    for (int k = 0; k < 64; ++k) {
        float w = Ws[k][col];
        a0 += xs[r0     ][k] * w;
        a1 += xs[r0 +  4][k] * w;
        a2 += xs[r0 +  8][k] * w;
        a3 += xs[r0 + 12][k] * w;
    }
    float av[4] = {a0, a1, a2, a3};
    #pragma unroll
    for (int j = 0; j < 4; ++j) {
        int rl = r0 + 4 * j;
        int r  = row0 + rl;
        hs[rl][col] = av[j];
        if (r < n) h[(size_t)r * 64 + col] = av[j];
    }
    __syncthreads();

    if (tid < 64) {
        int rl = tid >> 2;   // 0..15
        int hh = tid & 3;    // 0..3
        float s1 = 0.f, s2 = 0.f;
        #pragma unroll
        for (int d = 0; d < HD; ++d) {
            float v = hs[rl][hh * HD + d];
            s1 += v * attn_src[hh * HD + d];
            s2 += v * attn_dst[hh * HD + d];
        }
        int r = row0 + rl;
        if (r < n) {
            a_src[(size_t)r * 4 + hh] = s1;
            a_dst[(size_t)r * 4 + hh] = s2;
        }
    }
}

// ---------------------------------------------------------------------------
// Kernel 2: degree histogram over dst.
// ---------------------------------------------------------------------------
__global__ __launch_bounds__(256) void k_hist(
    const int* __restrict__ dst, int* __restrict__ deg, int E)
{
    int e = blockIdx.x * 256 + threadIdx.x;
    if (e < E) atomicAdd(&deg[dst[e]], 1);
}

// ---------------------------------------------------------------------------
// Scan kernels: exclusive prefix sum of deg[n] -> row_start[n] (+ cursor copy).
// Chunk = 1024 elements per 256-thread block (4 contiguous per thread).
// ---------------------------------------------------------------------------
__global__ __launch_bounds__(256) void k_scan_reduce(
    const int* __restrict__ deg, int* __restrict__ partials, int n)
{
    const int t = threadIdx.x;
    int idx = blockIdx.x * 1024 + t * 4;
    int s = 0;
    #pragma unroll
    for (int k = 0; k < 4; ++k) { int i = idx + k; if (i < n) s += deg[i]; }
    #pragma unroll
    for (int off = 32; off; off >>= 1) s += __shfl_xor(s, off, 64);
    __shared__ int wsum[4];
    if ((t & 63) == 0) wsum[t >> 6] = s;
    __syncthreads();
    if (t == 0) partials[blockIdx.x] = wsum[0] + wsum[1] + wsum[2] + wsum[3];
}

__global__ void k_scan_partials(int* __restrict__ partials, int nb)
{
    // single wave: 2 elements per lane, inclusive shfl scan -> exclusive
    int lane = threadIdx.x;
    int i0 = 2 * lane, i1 = 2 * lane + 1;
    int v0 = (i0 < nb) ? partials[i0] : 0;
    int v1 = (i1 < nb) ? partials[i1] : 0;
    int s = v0 + v1;
    int incl = s;
    #pragma unroll
    for (int off = 1; off < 64; off <<= 1) {
        int u = __shfl_up(incl, off, 64);
        if (lane >= off) incl += u;
    }
    int excl = incl - s;
    if (i0 < nb) partials[i0] = excl;
    if (i1 < nb) partials[i1] = excl + v0;
}

__global__ __launch_bounds__(256) void k_scan_final(
    const int* __restrict__ deg, const int* __restrict__ partials,
    int* __restrict__ row_start, int* __restrict__ cursor, int n)
{
    const int t = threadIdx.x;
    const int lane = t & 63, wid = t >> 6;
    int idx = blockIdx.x * 1024 + t * 4;
    int d0 = (idx     < n) ? deg[idx    ] : 0;
    int d1 = (idx + 1 < n) ? deg[idx + 1] : 0;
    int d2 = (idx + 2 < n) ? deg[idx + 2] : 0;
    int d3 = (idx + 3 < n) ? deg[idx + 3] : 0;
    int s = d0 + d1 + d2 + d3;
    int incl = s;
    #pragma unroll
    for (int off = 1; off < 64; off <<= 1) {
        int u = __shfl_up(incl, off, 64);
        if (lane >= off) incl += u;
    }
    __shared__ int wsum[4];
    if (lane == 63) wsum[wid] = incl;
    __syncthreads();
    int woff = 0;
    for (int i = 0; i < wid; ++i) woff += wsum[i];
    int p = partials[blockIdx.x] + woff + (incl - s);
    if (idx     < n) { row_start[idx    ] = p; cursor[idx    ] = p; } p += d0;
    if (idx + 1 < n) { row_start[idx + 1] = p; cursor[idx + 1] = p; } p += d1;
    if (idx + 2 < n) { row_start[idx + 2] = p; cursor[idx + 2] = p; } p += d2;
    if (idx + 3 < n) { row_start[idx + 3] = p; cursor[idx + 3] = p; }
}

// ---------------------------------------------------------------------------
// Kernel 3: fused edge score + CSR build.
// attn = lrelu(a_src[src] + a_dst[dst] + edge_attr @ W_edge); slot via
// atomicAdd(cursor[dst]); write csr_src / csr_attn at slot.
// ---------------------------------------------------------------------------
__global__ __launch_bounds__(256) void k_edge_build(
    const int* __restrict__ src, const int* __restrict__ dst,
    const float* __restrict__ ea, const float* __restrict__ We,
    const float* __restrict__ a_src, const float* __restrict__ a_dst,
    int* __restrict__ cursor, int* __restrict__ csr_src,
    float* __restrict__ csr_attn, int E)
{
    __shared__ float Wes[64];   // W_edge [16][4]
    const int tid = threadIdx.x;
    if (tid < 64) Wes[tid] = We[tid];
    __syncthreads();

    int e = blockIdx.x * 256 + tid;
    if (e >= E) return;

    int s = src[e];
    int d = dst[e];

    const float4* ea4 = (const float4*)(ea + (size_t)e * 16);
    float4 v0 = ea4[0], v1 = ea4[1], v2 = ea4[2], v3 = ea4[3];
    float eav[16] = {v0.x, v0.y, v0.z, v0.w, v1.x, v1.y, v1.z, v1.w,
                     v2.x, v2.y, v2.z, v2.w, v3.x, v3.y, v3.z, v3.w};
    float esc[H] = {0.f, 0.f, 0.f, 0.f};
    #pragma unroll
    for (int k = 0; k < 16; ++k) {
        #pragma unroll
        for (int hh = 0; hh < H; ++hh) esc[hh] += eav[k] * Wes[k * 4 + hh];
    }

    float4 as = *(const float4*)(a_src + (size_t)s * 4);
    float4 ad = *(const float4*)(a_dst + (size_t)d * 4);
    float a[4] = {as.x + ad.x + esc[0], as.y + ad.y + esc[1],
                  as.z + ad.z + esc[2], as.w + ad.w + esc[3]};
    #pragma unroll
    for (int hh = 0; hh < H; ++hh) a[hh] = (a[hh] >= 0.f) ? a[hh] : NEG_SLOPE * a[hh];

    int pos = atomicAdd(&cursor[d], 1);
    csr_src[pos] = s;
    *(float4*)(csr_attn + (size_t)pos * 4) = make_float4(a[0], a[1], a[2], a[3]);
}

// ---------------------------------------------------------------------------
// Kernel 4: wave-per-node gather aggregation + residual + LayerNorm.
// lane = column (head = lane/16). Unnormalized accumulate, divide once.
// ---------------------------------------------------------------------------
__global__ __launch_bounds__(256) void k_aggregate_ln(
    const int* __restrict__ row_start, const int* __restrict__ deg,
    const int* __restrict__ csr_src, const float* __restrict__ csr_attn,
    const float* __restrict__ h, const float* __restrict__ gamma,
    const float* __restrict__ beta, float* __restrict__ out, int n)
{
    int gid  = blockIdx.x * 256 + threadIdx.x;
    int node = gid >> 6;
    int lane = gid & 63;
    if (node >= n) return;
    int hh = lane >> 4;
    int rs = row_start[node];
    int dg = deg[node];

    // max over incoming edges, seeded with 0 (include_self semantics)
    float m = 0.f;
    for (int i = 0; i < dg; ++i)
        m = fmaxf(m, csr_attn[(size_t)(rs + i) * 4 + hh]);

    float sum = 0.f, accv = 0.f;
    for (int i = 0; i < dg; ++i) {
        int s   = csr_src[rs + i];
        float a = csr_attn[(size_t)(rs + i) * 4 + hh];
        float w = __expf(a - m);
        sum  += w;
        accv += w * h[(size_t)s * 64 + lane];
    }
    float y = accv / (sum + EPS_SM) + h[(size_t)node * 64 + lane];

    // LayerNorm across the 64 lanes
    float t1 = y;
    #pragma unroll
    for (int off = 32; off; off >>= 1) t1 += __shfl_xor(t1, off, 64);
    float mu = t1 * (1.f / 64.f);
    float dv = y - mu;
    float vs = dv * dv;
    #pragma unroll
    for (int off = 32; off; off >>= 1) vs += __shfl_xor(vs, off, 64);
    float var = vs * (1.f / 64.f);
    out[(size_t)node * 64 + lane] = dv * rsqrtf(var + EPS_LN) * gamma[lane] + beta[lane];
}

// ---------------------------------------------------------------------------
extern "C" void kernel_launch(void* const* d_in, const int* in_sizes, int n_in,
                              void* d_out, int out_size, void* d_ws, size_t ws_size,
                              hipStream_t stream)
{
    const float* x     = (const float*)d_in[0];
    const int*   ei    = (const int*)  d_in[1];
    const float* ea    = (const float*)d_in[2];
    const float* Wn    = (const float*)d_in[3];
    const float* We    = (const float*)d_in[4];
    const float* asrcW = (const float*)d_in[5];
    const float* adstW = (const float*)d_in[6];
    const float* gamma = (const float*)d_in[7];
    const float* beta  = (const float*)d_in[8];
    float* out = (float*)d_out;

    const int n = in_sizes[0] / 64;
    const int E = in_sizes[1] / 2;
    const int* src = ei;
    const int* dst = ei + E;
    const int nb = (n + 1023) / 1024;

    float* ws = (float*)d_ws;
    size_t off = 0;
    float* h_       = ws + off; off += (size_t)n * 64;
    float* a_src    = ws + off; off += (size_t)n * 4;
    float* a_dst    = ws + off; off += (size_t)n * 4;
    float* csr_attn = ws + off; off += (size_t)E * 4;
    int* ibase      = (int*)(ws + off);
    int* deg        = ibase;                 // n
    int* row_start  = ibase + n;             // n
    int* cursor     = ibase + 2 * (size_t)n; // n
    int* csr_src    = ibase + 3 * (size_t)n; // E
    int* partials   = ibase + 3 * (size_t)n + E; // nb

    hipMemsetAsync(deg, 0, (size_t)n * sizeof(int), stream);

    k_node<<<(n + 15) / 16, 256, 0, stream>>>(x, Wn, asrcW, adstW, h_, a_src, a_dst, n);
    k_hist<<<(E + 255) / 256, 256, 0, stream>>>(dst, deg, E);
    k_scan_reduce<<<nb, 256, 0, stream>>>(deg, partials, n);
    k_scan_partials<<<1, 64, 0, stream>>>(partials, nb);
    k_scan_final<<<nb, 256, 0, stream>>>(deg, partials, row_start, cursor, n);
    k_edge_build<<<(E + 255) / 256, 256, 0, stream>>>(src, dst, ea, We, a_src, a_dst,
                                                      cursor, csr_src, csr_attn, E);
    k_aggregate_ln<<<((size_t)n * 64 + 255) / 256, 256, 0, stream>>>(
        row_start, deg, csr_src, csr_attn, h_, gamma, beta, out, n);
}

// Round 3
// 350.483 us; speedup vs baseline: 2.6464x; 1.3441x over previous
//
#include <hip/hip_runtime.h>
#include <math.h>

#define H 4
#define HD 16
#define NEG_SLOPE 0.2f
#define EPS_SM 1e-8f
#define EPS_LN 1e-5f

// ---------------------------------------------------------------------------
// Kernel 1: h = x @ W_node (64x64), a_src[n][h] = <h[n,h,:], attn_src[h,:]>,
// a_dst likewise. 16 rows per 256-thread block; W_node staged in LDS.
// ---------------------------------------------------------------------------
__global__ __launch_bounds__(256) void k_node(
    const float* __restrict__ x, const float* __restrict__ Wn,
    const float* __restrict__ attn_src, const float* __restrict__ attn_dst,
    float* __restrict__ h, float* __restrict__ a_src, float* __restrict__ a_dst,
    int n)
{
    __shared__ float Ws[64][64];
    __shared__ float xs[16][64];
    __shared__ float hs[16][64];
    const int tid = threadIdx.x;
    const int row0 = blockIdx.x * 16;

    for (int i = tid; i < 64 * 64; i += 256) Ws[i >> 6][i & 63] = Wn[i];
    for (int i = tid; i < 16 * 64; i += 256) {
        int r = row0 + (i >> 6);
        xs[i >> 6][i & 63] = (r < n) ? x[(size_t)r * 64 + (i & 63)] : 0.f;
    }
    __syncthreads();

    const int col = tid & 63;
    const int r0  = tid >> 6;   // 0..3
    float a0 = 0.f, a1 = 0.f, a2 = 0.f, a3 = 0.f;
    #pragma unroll
    for (int k = 0; k < 64; ++k) {
        float w = Ws[k][col];
        a0 += xs[r0     ][k] * w;
        a1 += xs[r0 +  4][k] * w;
        a2 += xs[r0 +  8][k] * w;
        a3 += xs[r0 + 12][k] * w;
    }
    float av[4] = {a0, a1, a2, a3};
    #pragma unroll
    for (int j = 0; j < 4; ++j) {
        int rl = r0 + 4 * j;
        int r  = row0 + rl;
        hs[rl][col] = av[j];
        if (r < n) h[(size_t)r * 64 + col] = av[j];
    }
    __syncthreads();

    if (tid < 64) {
        int rl = tid >> 2;   // 0..15
        int hh = tid & 3;    // 0..3
        float s1 = 0.f, s2 = 0.f;
        #pragma unroll
        for (int d = 0; d < HD; ++d) {
            float v = hs[rl][hh * HD + d];
            s1 += v * attn_src[hh * HD + d];
            s2 += v * attn_dst[hh * HD + d];
        }
        int r = row0 + rl;
        if (r < n) {
            a_src[(size_t)r * 4 + hh] = s1;
            a_dst[(size_t)r * 4 + hh] = s2;
        }
    }
}

// ---------------------------------------------------------------------------
// Kernel 2: degree histogram over dst.
// ---------------------------------------------------------------------------
__global__ __launch_bounds__(256) void k_hist(
    const int* __restrict__ dst, int* __restrict__ deg, int E)
{
    int e = blockIdx.x * 256 + threadIdx.x;
    if (e < E) atomicAdd(&deg[dst[e]], 1);
}

// ---------------------------------------------------------------------------
// Scan kernels: exclusive prefix sum of deg[n] -> row_start[n] (+ cursor copy).
// ---------------------------------------------------------------------------
__global__ __launch_bounds__(256) void k_scan_reduce(
    const int* __restrict__ deg, int* __restrict__ partials, int n)
{
    const int t = threadIdx.x;
    int idx = blockIdx.x * 1024 + t * 4;
    int s = 0;
    #pragma unroll
    for (int k = 0; k < 4; ++k) { int i = idx + k; if (i < n) s += deg[i]; }
    #pragma unroll
    for (int off = 32; off; off >>= 1) s += __shfl_xor(s, off, 64);
    __shared__ int wsum[4];
    if ((t & 63) == 0) wsum[t >> 6] = s;
    __syncthreads();
    if (t == 0) partials[blockIdx.x] = wsum[0] + wsum[1] + wsum[2] + wsum[3];
}

__global__ void k_scan_partials(int* __restrict__ partials, int nb)
{
    int lane = threadIdx.x;
    int i0 = 2 * lane, i1 = 2 * lane + 1;
    int v0 = (i0 < nb) ? partials[i0] : 0;
    int v1 = (i1 < nb) ? partials[i1] : 0;
    int s = v0 + v1;
    int incl = s;
    #pragma unroll
    for (int off = 1; off < 64; off <<= 1) {
        int u = __shfl_up(incl, off, 64);
        if (lane >= off) incl += u;
    }
    int excl = incl - s;
    if (i0 < nb) partials[i0] = excl;
    if (i1 < nb) partials[i1] = excl + v0;
}

__global__ __launch_bounds__(256) void k_scan_final(
    const int* __restrict__ deg, const int* __restrict__ partials,
    int* __restrict__ row_start, int* __restrict__ cursor, int n)
{
    const int t = threadIdx.x;
    const int lane = t & 63, wid = t >> 6;
    int idx = blockIdx.x * 1024 + t * 4;
    int d0 = (idx     < n) ? deg[idx    ] : 0;
    int d1 = (idx + 1 < n) ? deg[idx + 1] : 0;
    int d2 = (idx + 2 < n) ? deg[idx + 2] : 0;
    int d3 = (idx + 3 < n) ? deg[idx + 3] : 0;
    int s = d0 + d1 + d2 + d3;
    int incl = s;
    #pragma unroll
    for (int off = 1; off < 64; off <<= 1) {
        int u = __shfl_up(incl, off, 64);
        if (lane >= off) incl += u;
    }
    __shared__ int wsum[4];
    if (lane == 63) wsum[wid] = incl;
    __syncthreads();
    int woff = 0;
    for (int i = 0; i < wid; ++i) woff += wsum[i];
    int p = partials[blockIdx.x] + woff + (incl - s);
    if (idx     < n) { row_start[idx    ] = p; cursor[idx    ] = p; } p += d0;
    if (idx + 1 < n) { row_start[idx + 1] = p; cursor[idx + 1] = p; } p += d1;
    if (idx + 2 < n) { row_start[idx + 2] = p; cursor[idx + 2] = p; } p += d2;
    if (idx + 3 < n) { row_start[idx + 3] = p; cursor[idx + 3] = p; }
}

// ---------------------------------------------------------------------------
// Kernel 3: fused edge score + CSR build.
// ---------------------------------------------------------------------------
__global__ __launch_bounds__(256) void k_edge_build(
    const int* __restrict__ src, const int* __restrict__ dst,
    const float* __restrict__ ea, const float* __restrict__ We,
    const float* __restrict__ a_src, const float* __restrict__ a_dst,
    int* __restrict__ cursor, int* __restrict__ csr_src,
    float* __restrict__ csr_attn, int E)
{
    __shared__ float Wes[64];   // W_edge [16][4]
    const int tid = threadIdx.x;
    if (tid < 64) Wes[tid] = We[tid];
    __syncthreads();

    int e = blockIdx.x * 256 + tid;
    if (e >= E) return;

    int s = src[e];
    int d = dst[e];

    const float4* ea4 = (const float4*)(ea + (size_t)e * 16);
    float4 v0 = ea4[0], v1 = ea4[1], v2 = ea4[2], v3 = ea4[3];
    float eav[16] = {v0.x, v0.y, v0.z, v0.w, v1.x, v1.y, v1.z, v1.w,
                     v2.x, v2.y, v2.z, v2.w, v3.x, v3.y, v3.z, v3.w};
    float esc[H] = {0.f, 0.f, 0.f, 0.f};
    #pragma unroll
    for (int k = 0; k < 16; ++k) {
        #pragma unroll
        for (int hh = 0; hh < H; ++hh) esc[hh] += eav[k] * Wes[k * 4 + hh];
    }

    float4 as = *(const float4*)(a_src + (size_t)s * 4);
    float4 ad = *(const float4*)(a_dst + (size_t)d * 4);
    float a[4] = {as.x + ad.x + esc[0], as.y + ad.y + esc[1],
                  as.z + ad.z + esc[2], as.w + ad.w + esc[3]};
    #pragma unroll
    for (int hh = 0; hh < H; ++hh) a[hh] = (a[hh] >= 0.f) ? a[hh] : NEG_SLOPE * a[hh];

    int pos = atomicAdd(&cursor[d], 1);
    csr_src[pos] = s;
    *(float4*)(csr_attn + (size_t)pos * 4) = make_float4(a[0], a[1], a[2], a[3]);
}

// ---------------------------------------------------------------------------
// Kernel 4: wave-per-node gather aggregation + residual + LayerNorm.
// Phase 1: wave-parallel coalesced float4 max (also warms L1 with attn rows).
// Phase 2: batched gathers — 64 src indices preloaded coalesced, shfl
// broadcast, 4x unroll for memory-level parallelism.
// ---------------------------------------------------------------------------
__global__ __launch_bounds__(256) void k_aggregate_ln(
    const int* __restrict__ row_start, const int* __restrict__ deg,
    const int* __restrict__ csr_src, const float* __restrict__ csr_attn,
    const float* __restrict__ h, const float* __restrict__ gamma,
    const float* __restrict__ beta, float* __restrict__ out, int n)
{
    int gid  = blockIdx.x * 256 + threadIdx.x;
    int node = gid >> 6;
    int lane = gid & 63;
    if (node >= n) return;
    int hh = lane >> 4;
    int rs = row_start[node];
    int dg = deg[node];

    // ---- phase 1: max over incoming edges, seeded 0 (include_self) ----
    float4 mx = make_float4(0.f, 0.f, 0.f, 0.f);
    for (int base = 0; base < dg; base += 64) {
        int i = base + lane;
        if (i < dg) {
            float4 a = ((const float4*)csr_attn)[(size_t)rs + i];
            mx.x = fmaxf(mx.x, a.x); mx.y = fmaxf(mx.y, a.y);
            mx.z = fmaxf(mx.z, a.z); mx.w = fmaxf(mx.w, a.w);
        }
    }
    #pragma unroll
    for (int off = 32; off; off >>= 1) {
        mx.x = fmaxf(mx.x, __shfl_xor(mx.x, off, 64));
        mx.y = fmaxf(mx.y, __shfl_xor(mx.y, off, 64));
        mx.z = fmaxf(mx.z, __shfl_xor(mx.z, off, 64));
        mx.w = fmaxf(mx.w, __shfl_xor(mx.w, off, 64));
    }
    float m = (hh == 0) ? mx.x : (hh == 1) ? mx.y : (hh == 2) ? mx.z : mx.w;

    // ---- phase 2: weighted gather-accumulate (unnormalized) ----
    float sum = 0.f, accv = 0.f;
    for (int base = 0; base < dg; base += 64) {
        int cnt = min(64, dg - base);
        int sidx = (base + lane < dg) ? csr_src[(size_t)rs + base + lane] : 0;
        int i = 0;
        for (; i + 4 <= cnt; i += 4) {
            int s0 = __shfl(sidx, i + 0, 64);
            int s1 = __shfl(sidx, i + 1, 64);
            int s2 = __shfl(sidx, i + 2, 64);
            int s3 = __shfl(sidx, i + 3, 64);
            float a0 = csr_attn[(size_t)(rs + base + i + 0) * 4 + hh];
            float a1 = csr_attn[(size_t)(rs + base + i + 1) * 4 + hh];
            float a2 = csr_attn[(size_t)(rs + base + i + 2) * 4 + hh];
            float a3 = csr_attn[(size_t)(rs + base + i + 3) * 4 + hh];
            float h0 = h[(size_t)s0 * 64 + lane];
            float h1 = h[(size_t)s1 * 64 + lane];
            float h2 = h[(size_t)s2 * 64 + lane];
            float h3 = h[(size_t)s3 * 64 + lane];
            float w0 = __expf(a0 - m), w1 = __expf(a1 - m);
            float w2 = __expf(a2 - m), w3 = __expf(a3 - m);
            sum  += (w0 + w1) + (w2 + w3);
            accv += w0 * h0 + w1 * h1 + w2 * h2 + w3 * h3;
        }
        for (; i < cnt; ++i) {
            int s = __shfl(sidx, i, 64);
            float a = csr_attn[(size_t)(rs + base + i) * 4 + hh];
            float w = __expf(a - m);
            sum  += w;
            accv += w * h[(size_t)s * 64 + lane];
        }
    }
    float y = accv / (sum + EPS_SM) + h[(size_t)node * 64 + lane];

    // ---- LayerNorm across the 64 lanes ----
    float t1 = y;
    #pragma unroll
    for (int off = 32; off; off >>= 1) t1 += __shfl_xor(t1, off, 64);
    float mu = t1 * (1.f / 64.f);
    float dv = y - mu;
    float vs = dv * dv;
    #pragma unroll
    for (int off = 32; off; off >>= 1) vs += __shfl_xor(vs, off, 64);
    float var = vs * (1.f / 64.f);
    out[(size_t)node * 64 + lane] = dv * rsqrtf(var + EPS_LN) * gamma[lane] + beta[lane];
}

// ---------------------------------------------------------------------------
extern "C" void kernel_launch(void* const* d_in, const int* in_sizes, int n_in,
                              void* d_out, int out_size, void* d_ws, size_t ws_size,
                              hipStream_t stream)
{
    const float* x     = (const float*)d_in[0];
    const int*   ei    = (const int*)  d_in[1];
    const float* ea    = (const float*)d_in[2];
    const float* Wn    = (const float*)d_in[3];
    const float* We    = (const float*)d_in[4];
    const float* asrcW = (const float*)d_in[5];
    const float* adstW = (const float*)d_in[6];
    const float* gamma = (const float*)d_in[7];
    const float* beta  = (const float*)d_in[8];
    float* out = (float*)d_out;

    const int n = in_sizes[0] / 64;
    const int E = in_sizes[1] / 2;
    const int* src = ei;
    const int* dst = ei + E;
    const int nb = (n + 1023) / 1024;

    float* ws = (float*)d_ws;
    size_t off = 0;
    float* h_       = ws + off; off += (size_t)n * 64;
    float* a_src    = ws + off; off += (size_t)n * 4;
    float* a_dst    = ws + off; off += (size_t)n * 4;
    float* csr_attn = ws + off; off += (size_t)E * 4;
    int* ibase      = (int*)(ws + off);
    int* deg        = ibase;                 // n
    int* row_start  = ibase + n;             // n
    int* cursor     = ibase + 2 * (size_t)n; // n
    int* csr_src    = ibase + 3 * (size_t)n; // E
    int* partials   = ibase + 3 * (size_t)n + E; // nb

    hipMemsetAsync(deg, 0, (size_t)n * sizeof(int), stream);

    k_node<<<(n + 15) / 16, 256, 0, stream>>>(x, Wn, asrcW, adstW, h_, a_src, a_dst, n);
    k_hist<<<(E + 255) / 256, 256, 0, stream>>>(dst, deg, E);
    k_scan_reduce<<<nb, 256, 0, stream>>>(deg, partials, n);
    k_scan_partials<<<1, 64, 0, stream>>>(partials, nb);
    k_scan_final<<<nb, 256, 0, stream>>>(deg, partials, row_start, cursor, n);
    k_edge_build<<<(E + 255) / 256, 256, 0, stream>>>(src, dst, ea, We, a_src, a_dst,
                                                      cursor, csr_src, csr_attn, E);
    k_aggregate_ln<<<((size_t)n * 64 + 255) / 256, 256, 0, stream>>>(
        row_start, deg, csr_src, csr_attn, h_, gamma, beta, out, n);
}